// Round 1
// baseline (3126.845 us; speedup 1.0000x reference)
//
#include <hip/hip_runtime.h>
#include <cstdint>
#include <cstddef>

#define BB   16
#define NN   4096
#define CINN 64
#define KKK  64
#define HIDD 128
#define SSS  1024
#define MAXC 512

// Exact f32 squared distance, numpy-style: ((dx*dx + dy*dy) + dz*dz), no FMA contraction.
__device__ __forceinline__ float d2_exact(float ax, float ay, float az,
                                          float bx, float by, float bz) {
  float dx = __fsub_rn(ax, bx);
  float dy = __fsub_rn(ay, by);
  float dz = __fsub_rn(az, bz);
  return __fadd_rn(__fadd_rn(__fmul_rn(dx, dx), __fmul_rn(dy, dy)), __fmul_rn(dz, dz));
}

// ---------------- FPS: one block per cloud ----------------
__global__ __launch_bounds__(1024) void fps_kernel(const float* __restrict__ pos,
                                                   int* __restrict__ fps_idx,
                                                   float* __restrict__ pos_out,
                                                   float* __restrict__ batch_out) {
  const int b = blockIdx.x;
  const int tid = threadIdx.x;
  const float* pb = pos + (size_t)b * NN * 3;
  __shared__ float px[NN], py[NN], pz[NN];
  __shared__ unsigned long long wred[16];
  __shared__ int s_last;

  for (int i = tid; i < NN; i += 1024) {
    px[i] = pb[i * 3 + 0];
    py[i] = pb[i * 3 + 1];
    pz[i] = pb[i * 3 + 2];
  }
  batch_out[b * SSS + tid] = (float)b;  // batch ids as f32 values
  if (tid == 0) { s_last = 0; fps_idx[b * SSS] = 0; }

  const int i0 = tid, i1 = tid + 1024, i2 = tid + 2048, i3 = tid + 3072;
  const unsigned n0 = ~(unsigned)i0, n1 = ~(unsigned)i1, n2 = ~(unsigned)i2, n3 = ~(unsigned)i3;
  float m0 = INFINITY, m1 = INFINITY, m2 = INFINITY, m3 = INFINITY;
  __syncthreads();
  if (tid == 0) {
    pos_out[(size_t)b * SSS * 3 + 0] = px[0];
    pos_out[(size_t)b * SSS * 3 + 1] = py[0];
    pos_out[(size_t)b * SSS * 3 + 2] = pz[0];
  }
  for (int t = 1; t < SSS; ++t) {
    const int last = s_last;
    const float lx = px[last], ly = py[last], lz = pz[last];
    m0 = fminf(m0, d2_exact(px[i0], py[i0], pz[i0], lx, ly, lz));
    m1 = fminf(m1, d2_exact(px[i1], py[i1], pz[i1], lx, ly, lz));
    m2 = fminf(m2, d2_exact(px[i2], py[i2], pz[i2], lx, ly, lz));
    m3 = fminf(m3, d2_exact(px[i3], py[i3], pz[i3], lx, ly, lz));
    // key = (min_d bits << 32) | ~idx : max key == (max val, lowest idx) == jnp.argmax
    unsigned long long k0 = ((unsigned long long)__float_as_uint(m0) << 32) | n0;
    unsigned long long k1 = ((unsigned long long)__float_as_uint(m1) << 32) | n1;
    unsigned long long k2 = ((unsigned long long)__float_as_uint(m2) << 32) | n2;
    unsigned long long k3 = ((unsigned long long)__float_as_uint(m3) << 32) | n3;
    unsigned long long best = k0 > k1 ? k0 : k1;
    best = k2 > best ? k2 : best;
    best = k3 > best ? k3 : best;
    #pragma unroll
    for (int off = 32; off > 0; off >>= 1) {
      unsigned long long o = __shfl_xor(best, off, 64);
      best = o > best ? o : best;
    }
    if ((tid & 63) == 0) wred[tid >> 6] = best;
    __syncthreads();
    if (tid == 0) {
      unsigned long long mm = wred[0];
      #pragma unroll
      for (int w = 1; w < 16; ++w) mm = wred[w] > mm ? wred[w] : mm;
      const int sel = (int)(~(unsigned)(mm & 0xffffffffull));
      s_last = sel;
      fps_idx[b * SSS + t] = sel;
      pos_out[((size_t)b * SSS + t) * 3 + 0] = px[sel];
      pos_out[((size_t)b * SSS + t) * 3 + 1] = py[sel];
      pos_out[((size_t)b * SSS + t) * 3 + 2] = pz[sel];
    }
    __syncthreads();
  }
}

// ---------------- y1 = x @ W1[0:64,:]  (precompute, no bias) ----------------
__global__ __launch_bounds__(256) void y1_kernel(const float* __restrict__ x,
                                                 const float* __restrict__ W1,
                                                 float* __restrict__ y1) {
  const int p0 = blockIdx.x * 8;
  const int tid = threadIdx.x;
  __shared__ float sW[CINN][HIDD];  // 32KB
  __shared__ float sx[8][CINN];     // 2KB
  for (int e = tid; e < CINN * HIDD; e += 256) (&sW[0][0])[e] = W1[e];
  for (int e = tid; e < 8 * CINN; e += 256) {
    const int p = e >> 6, c = e & 63;
    sx[p][c] = x[(size_t)(p0 + p) * CINN + c];
  }
  __syncthreads();
  const int h = tid & 127;
  const int pg = (tid >> 7) * 4;
  float a0 = 0.f, a1 = 0.f, a2 = 0.f, a3 = 0.f;
  for (int c = 0; c < CINN; ++c) {
    const float w = sW[c][h];
    a0 = fmaf(sx[pg + 0][c], w, a0);
    a1 = fmaf(sx[pg + 1][c], w, a1);
    a2 = fmaf(sx[pg + 2][c], w, a2);
    a3 = fmaf(sx[pg + 3][c], w, a3);
  }
  y1[(size_t)(p0 + pg + 0) * HIDD + h] = a0;
  y1[(size_t)(p0 + pg + 1) * HIDD + h] = a1;
  y1[(size_t)(p0 + pg + 2) * HIDD + h] = a2;
  y1[(size_t)(p0 + pg + 3) * HIDD + h] = a3;
}

// ---------------- fused ball query + MLP + max: one block per center ----------------
__global__ __launch_bounds__(256) void bq_mlp_kernel(const float* __restrict__ pos,
                                                     const float* __restrict__ y1,
                                                     const float* __restrict__ W1,
                                                     const float* __restrict__ b1,
                                                     const float* __restrict__ W2,
                                                     const float* __restrict__ b2,
                                                     const int* __restrict__ fps_idx,
                                                     float* __restrict__ out) {
  const int g = blockIdx.x;      // center id, 0..B*S-1
  const int b = g >> 10;         // cloud id (S=1024)
  const int tid = threadIdx.x;
  __shared__ float s_w2[HIDD][HIDD];  // 64KB
  __shared__ float s_h1[HIDD][68];    // transposed [h][k], padded; 34.8KB
  __shared__ float s_cd[MAXC];
  __shared__ int   s_ci[MAXC];
  __shared__ int   s_sel[KKK];
  __shared__ int   s_cnt, s_scnt;

  for (int e = tid; e < HIDD * HIDD; e += 256) (&s_w2[0][0])[e] = W2[e];
  if (tid == 0) { s_cnt = 0; s_scnt = 0; }

  const float* pb = pos + (size_t)b * NN * 3;
  const int cpt = fps_idx[g];
  const float cx = pb[cpt * 3 + 0], cy = pb[cpt * 3 + 1], cz = pb[cpt * 3 + 2];
  __syncthreads();

  // phase 1: radius filter + compaction (order nondeterministic, set deterministic)
  for (int i = tid; i < NN; i += 256) {
    const float d2 = d2_exact(pb[i * 3 + 0], pb[i * 3 + 1], pb[i * 3 + 2], cx, cy, cz);
    if (d2 <= 0.04f) {
      const int slot = atomicAdd(&s_cnt, 1);
      if (slot < MAXC) { s_cd[slot] = d2; s_ci[slot] = i; }
    }
  }
  __syncthreads();
  const int C = min(s_cnt, MAXC);

  // phase 2: exact lex-rank (d2, idx) selection of K smallest == lax.top_k tie-break
  for (int j = tid; j < C; j += 256) {
    const float dj = s_cd[j];
    const int ij = s_ci[j];
    int rank = 0;
    for (int m = 0; m < C; ++m) {
      const float dm = s_cd[m];
      const int im = s_ci[m];
      rank += (dm < dj || (dm == dj && im < ij)) ? 1 : 0;
    }
    if (rank < KKK) s_sel[atomicAdd(&s_scnt, 1)] = ij;
  }
  // zero h1 (covers k >= M rows)
  for (int e = tid; e < HIDD * 68; e += 256) (&s_h1[0][0])[e] = 0.f;
  __syncthreads();
  const int M = s_scnt;  // = min(C, K) >= 1 (center itself is in-radius)

  // phase 3: h1[k][h] = relu(y1[p][h] + b1[h] + rel . W1[64:67][h]) stored transposed
  for (int e = tid; e < M * HIDD; e += 256) {
    const int k = e >> 7, h = e & 127;
    const int p = s_sel[k];
    const float rx = pb[p * 3 + 0] - cx;
    const float ry = pb[p * 3 + 1] - cy;
    const float rz = pb[p * 3 + 2] - cz;
    float v = y1[((size_t)(b * NN + p)) * HIDD + h] + b1[h];
    v += rx * W1[64 * HIDD + h];
    v += ry * W1[65 * HIDD + h];
    v += rz * W1[66 * HIDD + h];
    s_h1[h][k] = fmaxf(v, 0.f);
  }
  __syncthreads();

  // phase 4: h2 = relu(h1 @ W2 + b2), col-max over valid k. 4k x 8c per thread.
  const int c0 = (tid & 15) * 8;
  const int k0 = (tid >> 4) * 4;
  float acc[4][8];
  #pragma unroll
  for (int j = 0; j < 4; ++j)
    #pragma unroll
    for (int c = 0; c < 8; ++c) acc[j][c] = 0.f;

  for (int h = 0; h < HIDD; ++h) {
    const float4 a  = *(const float4*)&s_h1[h][k0];
    const float4 w0 = *(const float4*)&s_w2[h][c0];
    const float4 w1 = *(const float4*)&s_w2[h][c0 + 4];
    const float av[4] = {a.x, a.y, a.z, a.w};
    const float wv[8] = {w0.x, w0.y, w0.z, w0.w, w1.x, w1.y, w1.z, w1.w};
    #pragma unroll
    for (int j = 0; j < 4; ++j)
      #pragma unroll
      for (int c = 0; c < 8; ++c)
        acc[j][c] = fmaf(av[j], wv[c], acc[j][c]);
  }

  float mx[8];
  #pragma unroll
  for (int c = 0; c < 8; ++c) mx[c] = 0.f;  // relu >= 0 and >=1 valid k => exact
  #pragma unroll
  for (int j = 0; j < 4; ++j) {
    if (k0 + j < M) {
      #pragma unroll
      for (int c = 0; c < 8; ++c) {
        const float v = fmaxf(acc[j][c] + b2[c0 + c], 0.f);
        mx[c] = fmaxf(mx[c], v);
      }
    }
  }
  __syncthreads();  // all reads of s_h1 done; reuse as reduction buffer
  #pragma unroll
  for (int c = 0; c < 8; ++c) s_h1[c0 + c][tid >> 4] = mx[c];
  __syncthreads();
  if (tid < HIDD) {
    float m = 0.f;
    #pragma unroll
    for (int w = 0; w < 16; ++w) m = fmaxf(m, s_h1[tid][w]);
    out[(size_t)g * HIDD + tid] = m;
  }
}

extern "C" void kernel_launch(void* const* d_in, const int* in_sizes, int n_in,
                              void* d_out, int out_size, void* d_ws, size_t ws_size,
                              hipStream_t stream) {
  const float* x   = (const float*)d_in[0];
  const float* pos = (const float*)d_in[1];
  // d_in[2] = batch ids (unused; layout is implicit: sorted, N per cloud)
  const float* W1 = (const float*)d_in[3];
  const float* b1 = (const float*)d_in[4];
  const float* W2 = (const float*)d_in[5];
  const float* b2 = (const float*)d_in[6];

  float* out       = (float*)d_out;                       // [B*S, HID]
  float* pos_out   = out + (size_t)BB * SSS * HIDD;       // [B*S, 3]
  float* batch_out = pos_out + (size_t)BB * SSS * 3;      // [B*S] (as f32 values)

  int*   fps_idx = (int*)d_ws;                            // [B*S]
  float* y1      = (float*)((char*)d_ws + (1 << 20));     // [B*N, HID] = 32MB

  fps_kernel<<<BB, 1024, 0, stream>>>(pos, fps_idx, pos_out, batch_out);
  y1_kernel<<<(BB * NN) / 8, 256, 0, stream>>>(x, W1, y1);
  bq_mlp_kernel<<<BB * SSS, 256, 0, stream>>>(pos, y1, W1, b1, W2, b2, fps_idx, out);
}

// Round 3
// 1285.981 us; speedup vs baseline: 2.4315x; 2.4315x over previous
//
#include <hip/hip_runtime.h>
#include <cstdint>
#include <cstddef>

#define BB   16
#define NN   4096
#define CINN 64
#define KKK  64
#define HIDD 128
#define SSS  1024
#define MAXC 512

typedef __attribute__((ext_vector_type(8))) short short8;
typedef __attribute__((ext_vector_type(4))) float f32x4;
typedef unsigned long long u64;

// Exact f32 squared distance, numpy-style: ((dx*dx + dy*dy) + dz*dz), no FMA contraction.
// MUST stay bit-identical to round-1 (absmax 0.0 proved selection equivalence).
__device__ __forceinline__ float d2_exact(float ax, float ay, float az,
                                          float bx, float by, float bz) {
  float dx = __fsub_rn(ax, bx);
  float dy = __fsub_rn(ay, by);
  float dz = __fsub_rn(az, bz);
  return __fadd_rn(__fadd_rn(__fmul_rn(dx, dx), __fmul_rn(dy, dy)), __fmul_rn(dz, dz));
}

// f32 -> bf16 round-to-nearest-even (no NaN inputs here)
__device__ __forceinline__ unsigned short f2bf(float f) {
  unsigned u = __float_as_uint(f);
  return (unsigned short)((u + 0x7fffu + ((u >> 16) & 1u)) >> 16);
}

// ============ K1: heterogeneous launch: FPS (blocks 0..15) || y1 (16..8207) || W2 cvt (8208) ============
__global__ __launch_bounds__(256) void k1_kernel(const float* __restrict__ x,
                                                 const float* __restrict__ pos,
                                                 const float* __restrict__ W1,
                                                 const float* __restrict__ W2,
                                                 int* __restrict__ fps_idx,
                                                 float* __restrict__ y1,
                                                 unsigned short* __restrict__ W2t,
                                                 float* __restrict__ pos_out,
                                                 float* __restrict__ batch_out) {
  __shared__ __align__(16) char smem[49280];
  const int tid = threadIdx.x;
  const int bid = blockIdx.x;

  if (bid < BB) {
    // ---------------- FPS: 256 threads, 16 points/thread in registers ----------------
    float* px = (float*)smem;
    float* py = px + NN;
    float* pz = py + NN;
    u64* slots = (u64*)(pz + NN);  // [2][4] parity-double-buffered wave leaders
    const float* pb = pos + (size_t)bid * NN * 3;
    for (int i = tid; i < NN; i += 256) {
      px[i] = pb[3 * i + 0];
      py[i] = pb[3 * i + 1];
      pz[i] = pb[3 * i + 2];
    }
    #pragma unroll
    for (int kk = 0; kk < 4; ++kk)
      batch_out[bid * SSS + kk * 256 + tid] = (float)bid;
    __syncthreads();

    float qx[16], qy[16], qz[16], md[16];
    #pragma unroll
    for (int j = 0; j < 16; ++j) {
      const int i = j * 256 + tid;
      qx[j] = px[i]; qy[j] = py[i]; qz[j] = pz[i];
      md[j] = __builtin_inff();
    }
    int last = 0;
    if (tid == 0) {
      fps_idx[bid * SSS] = 0;
      pos_out[(size_t)bid * SSS * 3 + 0] = px[0];
      pos_out[(size_t)bid * SSS * 3 + 1] = py[0];
      pos_out[(size_t)bid * SSS * 3 + 2] = pz[0];
    }
    for (int t = 1; t < SSS; ++t) {
      const float lx = px[last], ly = py[last], lz = pz[last];
      float bv = -1.f;
      int bj = 0;
      #pragma unroll
      for (int j = 0; j < 16; ++j) {
        const float d = d2_exact(qx[j], qy[j], qz[j], lx, ly, lz);
        md[j] = fminf(md[j], d);
        if (md[j] > bv) { bv = md[j]; bj = j; }  // strict > : lowest j among ties
      }
      // key = (valbits<<32) | ~idx : u64 max == (max val, lowest idx) == jnp.argmax
      u64 key = ((u64)__float_as_uint(bv) << 32) | (unsigned)(~(bj * 256 + tid));
      #pragma unroll
      for (int off = 32; off >= 1; off >>= 1) {
        u64 o = __shfl_xor(key, off, 64);
        key = o > key ? o : key;
      }
      u64* sl = slots + (t & 1) * 4;
      if ((tid & 63) == 0) sl[tid >> 6] = key;
      __syncthreads();  // single barrier per step (parity buffers kill the WAR hazard)
      u64 k0 = sl[0], k1 = sl[1], k2 = sl[2], k3 = sl[3];
      k0 = k1 > k0 ? k1 : k0;
      k2 = k3 > k2 ? k3 : k2;
      k0 = k2 > k0 ? k2 : k0;
      last = (int)(~(unsigned)(k0 & 0xffffffffull));
      if (tid == 0) {
        fps_idx[bid * SSS + t] = last;
        pos_out[((size_t)bid * SSS + t) * 3 + 0] = px[last];
        pos_out[((size_t)bid * SSS + t) * 3 + 1] = py[last];
        pos_out[((size_t)bid * SSS + t) * 3 + 2] = pz[last];
      }
    }
  } else if (bid < 16 + 8192) {
    // ---------------- y1 = x @ W1[0:64,:]  (8 points per block) ----------------
    float* sW = (float*)smem;             // [64][128]
    float* sx = (float*)(smem + 32768);   // [8][64]
    const int p0 = (bid - 16) * 8;
    for (int e = tid; e < CINN * HIDD; e += 256) sW[e] = W1[e];
    for (int e = tid; e < 8 * CINN; e += 256) sx[e] = x[(size_t)p0 * CINN + e];
    __syncthreads();
    const int h = tid & 127;
    const int pg = (tid >> 7) * 4;
    float a0 = 0.f, a1 = 0.f, a2 = 0.f, a3 = 0.f;
    for (int c = 0; c < CINN; ++c) {
      const float w = sW[c * HIDD + h];
      a0 = fmaf(sx[(pg + 0) * CINN + c], w, a0);
      a1 = fmaf(sx[(pg + 1) * CINN + c], w, a1);
      a2 = fmaf(sx[(pg + 2) * CINN + c], w, a2);
      a3 = fmaf(sx[(pg + 3) * CINN + c], w, a3);
    }
    y1[(size_t)(p0 + pg + 0) * HIDD + h] = a0;
    y1[(size_t)(p0 + pg + 1) * HIDD + h] = a1;
    y1[(size_t)(p0 + pg + 2) * HIDD + h] = a2;
    y1[(size_t)(p0 + pg + 3) * HIDD + h] = a3;
  } else {
    // ---------------- W2 -> W2^T bf16 (for MFMA B-operand) ----------------
    for (int e = tid; e < HIDD * HIDD; e += 256) {
      const int n = e >> 7, hh = e & 127;
      W2t[e] = f2bf(W2[hh * HIDD + n]);   // W2t[n][h]
    }
  }
}

// ============ K2: ball query per center -> nbr set + count (order-free set, exact selection) ============
__global__ __launch_bounds__(256) void bq_kernel(const float* __restrict__ pos,
                                                 const int* __restrict__ fps_idx,
                                                 int* __restrict__ nbr,
                                                 int* __restrict__ cnt) {
  const int g = blockIdx.x, b = g >> 10, tid = threadIdx.x;
  __shared__ float s_cd[MAXC];
  __shared__ int s_ci[MAXC];
  __shared__ int s_cnt, s_scnt;
  if (tid == 0) { s_cnt = 0; s_scnt = 0; }
  const float* pb = pos + (size_t)b * NN * 3;
  const int cpt = fps_idx[g];
  const float cx = pb[cpt * 3 + 0], cy = pb[cpt * 3 + 1], cz = pb[cpt * 3 + 2];
  __syncthreads();
  for (int i = tid; i < NN; i += 256) {
    const float d2 = d2_exact(pb[i * 3 + 0], pb[i * 3 + 1], pb[i * 3 + 2], cx, cy, cz);
    if (d2 <= 0.04f) {
      const int slot = atomicAdd(&s_cnt, 1);
      if (slot < MAXC) { s_cd[slot] = d2; s_ci[slot] = i; }
    }
  }
  __syncthreads();
  const int C = min(s_cnt, MAXC);
  // exact lex-rank (d2, idx) == lax.top_k tie-break; order-independent
  for (int j = tid; j < C; j += 256) {
    const float dj = s_cd[j];
    const int ij = s_ci[j];
    int rank = 0;
    for (int m = 0; m < C; ++m) {
      const float dm = s_cd[m];
      const int im = s_ci[m];
      rank += (dm < dj || (dm == dj && im < ij)) ? 1 : 0;
    }
    if (rank < KKK) nbr[(size_t)g * KKK + atomicAdd(&s_scnt, 1)] = ij;
  }
  __syncthreads();
  if (tid == 0) cnt[g] = s_scnt;
}

// ============ K3: gather + layer1-correction + bf16 MFMA layer2 + masked max. 2 centers/block ============
__global__ __launch_bounds__(256) void mlp_kernel(const float* __restrict__ pos,
                                                  const float* __restrict__ y1,
                                                  const float* __restrict__ W1,
                                                  const float* __restrict__ b1,
                                                  const unsigned short* __restrict__ W2t,
                                                  const float* __restrict__ b2,
                                                  const int* __restrict__ fps_idx,
                                                  const int* __restrict__ nbr,
                                                  const int* __restrict__ cnt,
                                                  float* __restrict__ out) {
  __shared__ __align__(16) char smem[65536];  // [0,32K)=W2t bf16 swz, [32K,64K)=h1 bf16 swz
  __shared__ float s_ctr[2][3];
  __shared__ int s_M[2];
  const int tid = threadIdx.x;
  const int g0 = blockIdx.x * 2;
  const int b = g0 >> 10;

  // stage W2t (128 rows x 256B, 16 uint4/row) with 16B XOR swizzle (T2)
  for (int c = tid; c < 2048; c += 256) {
    const int row = c >> 4;
    const int col = (c & 15) << 4;
    const uint4 v = ((const uint4*)W2t)[c];
    *(uint4*)(smem + row * 256 + (col ^ ((row & 7) << 4))) = v;
  }
  if (tid < 2) {
    s_M[tid] = min(cnt[g0 + tid], KKK);
    const int cp = fps_idx[g0 + tid];
    s_ctr[tid][0] = pos[((size_t)b * NN + cp) * 3 + 0];
    s_ctr[tid][1] = pos[((size_t)b * NN + cp) * 3 + 1];
    s_ctr[tid][2] = pos[((size_t)b * NN + cp) * 3 + 2];
  }
  __syncthreads();

  const int wv = tid >> 6, ln = tid & 63;
  // per-lane layer-1 constants for cols (2*ln, 2*ln+1) — loaded once, reused for 32 rows
  const float2 b1v = *(const float2*)(b1 + ln * 2);
  const float2 wav = *(const float2*)(W1 + 64 * HIDD + ln * 2);
  const float2 wbv = *(const float2*)(W1 + 65 * HIDD + ln * 2);
  const float2 wcv = *(const float2*)(W1 + 66 * HIDD + ln * 2);
  char* Hb = smem + 32768;
  for (int r = wv * 32; r < wv * 32 + 32; ++r) {   // row r: center r>>6, neighbor k=r&63
    const int ci = r >> 6, k = r & 63;
    unsigned val = 0u;
    if (k < s_M[ci]) {
      const int p = nbr[(size_t)(g0 + ci) * KKK + k];
      const float rx = pos[((size_t)b * NN + p) * 3 + 0] - s_ctr[ci][0];
      const float ry = pos[((size_t)b * NN + p) * 3 + 1] - s_ctr[ci][1];
      const float rz = pos[((size_t)b * NN + p) * 3 + 2] - s_ctr[ci][2];
      const float2 yv = *(const float2*)(y1 + ((size_t)(b * NN + p)) * HIDD + ln * 2);
      float v0 = fmaxf(yv.x + b1v.x + rx * wav.x + ry * wbv.x + rz * wcv.x, 0.f);
      float v1 = fmaxf(yv.y + b1v.y + rx * wav.y + ry * wbv.y + rz * wcv.y, 0.f);
      val = (unsigned)f2bf(v0) | ((unsigned)f2bf(v1) << 16);
    }
    *(unsigned*)(Hb + r * 256 + ((ln * 4) ^ ((r & 7) << 4))) = val;
  }
  __syncthreads();

  // MFMA: wave (mw=center, nw=col-half); 4x4 16x16 tiles; K=128 in 4 steps of 32.
  // Frag layout (contiguous-8 K, per m92 ref-checked ds_read_b128 pattern):
  //   A: lane -> row=l&15, k=(l>>4)*8+e ; B: k=(l>>4)*8+e, col=l&15 (via transposed W2t rows)
  const int mw = wv >> 1, nw = wv & 1;
  const int lr = ln & 15, lg = ln >> 4;
  f32x4 zero = {0.f, 0.f, 0.f, 0.f};
  f32x4 acc[4][4];
  #pragma unroll
  for (int mi = 0; mi < 4; ++mi)
    #pragma unroll
    for (int ni = 0; ni < 4; ++ni) acc[mi][ni] = zero;

  #pragma unroll
  for (int ks = 0; ks < 4; ++ks) {
    short8 af[4], bf_[4];
    #pragma unroll
    for (int mi = 0; mi < 4; ++mi) {
      const int row = mw * 64 + mi * 16 + lr;
      af[mi] = *(const short8*)(Hb + row * 256 + ((ks * 64 + lg * 16) ^ ((row & 7) << 4)));
    }
    #pragma unroll
    for (int ni = 0; ni < 4; ++ni) {
      const int row = nw * 64 + ni * 16 + lr;
      bf_[ni] = *(const short8*)(smem + row * 256 + ((ks * 64 + lg * 16) ^ ((row & 7) << 4)));
    }
    #pragma unroll
    for (int mi = 0; mi < 4; ++mi)
      #pragma unroll
      for (int ni = 0; ni < 4; ++ni)
        acc[mi][ni] = __builtin_amdgcn_mfma_f32_16x16x32_bf16(af[mi], bf_[ni], acc[mi][ni], 0, 0, 0);
  }

  // epilogue: relu(acc+b2), mask k>=M to 0 (relu>=0 and k=0 always valid => exact), max over k
  const int cId = g0 + mw;
  const int Mc = s_M[mw];
  #pragma unroll
  for (int ni = 0; ni < 4; ++ni) {
    const float b2v = b2[nw * 64 + ni * 16 + lr];
    float cm = 0.f;
    #pragma unroll
    for (int mi = 0; mi < 4; ++mi)
      #pragma unroll
      for (int rr = 0; rr < 4; ++rr) {
        const int k = mi * 16 + lg * 4 + rr;   // C layout: col=lane&15, row=(lane>>4)*4+reg
        const float v = fmaxf(acc[mi][ni][rr] + b2v, 0.f);
        cm = fmaxf(cm, k < Mc ? v : 0.f);
      }
    cm = fmaxf(cm, __shfl_xor(cm, 16, 64));
    cm = fmaxf(cm, __shfl_xor(cm, 32, 64));
    if (ln < 16) out[(size_t)cId * HIDD + nw * 64 + ni * 16 + lr] = cm;
  }
}

extern "C" void kernel_launch(void* const* d_in, const int* in_sizes, int n_in,
                              void* d_out, int out_size, void* d_ws, size_t ws_size,
                              hipStream_t stream) {
  const float* x   = (const float*)d_in[0];
  const float* pos = (const float*)d_in[1];
  const float* W1  = (const float*)d_in[3];
  const float* b1  = (const float*)d_in[4];
  const float* W2  = (const float*)d_in[5];
  const float* b2  = (const float*)d_in[6];

  float* out       = (float*)d_out;                   // [B*S, HID]
  float* pos_out   = out + (size_t)BB * SSS * HIDD;   // [B*S, 3]
  float* batch_out = pos_out + (size_t)BB * SSS * 3;  // [B*S]

  int* fps_idx            = (int*)d_ws;                                  // 64 KB
  int* cnt                = (int*)((char*)d_ws + 65536);                 // 64 KB
  unsigned short* W2t     = (unsigned short*)((char*)d_ws + 131072);     // 32 KB
  int* nbr                = (int*)((char*)d_ws + 262144);                // 4 MB
  float* y1               = (float*)((char*)d_ws + 262144 + 4194304);    // 32 MB

  k1_kernel<<<16 + 8192 + 1, 256, 0, stream>>>(x, pos, W1, W2, fps_idx, y1, W2t,
                                               pos_out, batch_out);
  bq_kernel<<<BB * SSS, 256, 0, stream>>>(pos, fps_idx, nbr, cnt);
  mlp_kernel<<<BB * SSS / 2, 256, 0, stream>>>(pos, y1, W1, b1, W2t, b2,
                                               fps_idx, nbr, cnt, out);
}